// Round 1
// baseline (211.907 us; speedup 1.0000x reference)
//
#include <hip/hip_runtime.h>

// Deinterleave x[B,C,H,W] (fp32, H=W=256) into 4 quadrant tensors:
//   ll = x[:,:,0::2,0::2], lh = x[:,:,0::2,1::2],
//   hl = x[:,:,1::2,0::2], hh = x[:,:,1::2,1::2]
// d_out = [ll | lh | hl | hh] flat, each of size B*C*128*128.
//
// Pure memory-bound permutation. Each thread handles 8 consecutive input
// floats (two float4 loads), emits one float4 of even cols and one float4
// of odd cols.

__global__ __launch_bounds__(256) void deinterleave2x2_kernel(
    const float4* __restrict__ in,   // input viewed as float4
    float* __restrict__ out,         // base of concatenated outputs
    size_t nquads,                   // total 8-float quads = N/8
    size_t outsz)                    // elements per output tensor
{
    const size_t stride = (size_t)gridDim.x * blockDim.x;
    for (size_t q = (size_t)blockIdx.x * blockDim.x + threadIdx.x;
         q < nquads; q += stride) {
        // Two contiguous float4 loads = 8 consecutive floats of one row.
        float4 a = in[2 * q];
        float4 b = in[2 * q + 1];

        // Row geometry: W=256 floats -> 32 quads per row; H=256 rows/image.
        size_t row = q >> 5;          // global row index (img*256 + h)
        size_t c8  = q & 31;          // quad index within the row
        size_t h   = row & 255;       // row within image
        size_t img = row >> 8;        // which (b, c) image

        // Output: 128x128 per image; 8 input cols -> 4 output cols.
        size_t off = img * (size_t)(128 * 128) + (h >> 1) * 128 + c8 * 4;

        int p = (int)(h & 1);         // row parity: 0 -> ll/lh, 1 -> hl/hh

        float4 ev = make_float4(a.x, a.z, b.x, b.z);   // even cols
        float4 od = make_float4(a.y, a.w, b.y, b.w);   // odd cols

        float* ev_base = out + (size_t)(p ? 2 : 0) * outsz;  // ll or hl
        float* od_base = out + (size_t)(p ? 3 : 1) * outsz;  // lh or hh

        *reinterpret_cast<float4*>(ev_base + off) = ev;
        *reinterpret_cast<float4*>(od_base + off) = od;
    }
}

extern "C" void kernel_launch(void* const* d_in, const int* in_sizes, int n_in,
                              void* d_out, int out_size, void* d_ws, size_t ws_size,
                              hipStream_t stream) {
    const float* x = (const float*)d_in[0];
    float* out = (float*)d_out;

    const size_t total  = (size_t)in_sizes[0];      // B*C*H*W = 8*256*256*256
    const size_t nquads = total >> 3;               // 8 floats per thread-iter
    const size_t outsz  = total >> 2;               // each output = total/4

    const int threads = 256;
    const int blocks  = 2048;                        // ~8 blocks/CU on 256 CUs

    deinterleave2x2_kernel<<<blocks, threads, 0, stream>>>(
        reinterpret_cast<const float4*>(x), out, nquads, outsz);
}

// Round 3
// 194.808 us; speedup vs baseline: 1.0878x; 1.0878x over previous
//
#include <hip/hip_runtime.h>

// Deinterleave x[B,C,H,W] (fp32, H=W=256) into 4 quadrant tensors:
//   ll = x[:,:,0::2,0::2], lh = x[:,:,0::2,1::2],
//   hl = x[:,:,1::2,0::2], hh = x[:,:,1::2,1::2]
// d_out = [ll | lh | hl | hh] flat, each of size B*C*128*128 floats.
//
// Layout: one work-item = (row-pair p, lane l). A 64-lane wave covers one
// full row-pair:
//   load  e = in_v4[128p + l]        -> even row, 1KB contiguous per wave
//   load  o = in_v4[128p + 64 + l]   -> odd row,  1KB contiguous per wave
//   store 4x 8B vec, one per quadrant -> 512B contiguous per wave each
// All accesses dense + aligned; non-temporal since there is zero reuse.
//
// Note: __builtin_nontemporal_* requires Clang ext_vector types, not the
// HIP_vector_type structs (float4/float2) — hence f32x4/f32x2 below.

typedef float f32x4 __attribute__((ext_vector_type(4)));
typedef float f32x2 __attribute__((ext_vector_type(2)));

__global__ __launch_bounds__(256) void deinterleave2x2_kernel(
    const f32x4* __restrict__ in,    // input viewed as 16B vectors
    float* __restrict__ out,         // base of concatenated outputs
    size_t nitems,                   // total work items = N/8
    size_t outsz)                    // elements per output tensor
{
    const size_t stride = (size_t)gridDim.x * blockDim.x;
    for (size_t t = (size_t)blockIdx.x * blockDim.x + threadIdx.x;
         t < nitems; t += stride) {
        const size_t l   = t & 63;          // lane-within-row-pair
        const size_t p   = t >> 6;          // global row-pair index
        const size_t hp  = p & 127;         // row-pair within image
        const size_t img = p >> 7;          // which (b,c) image

        // Even row 2p starts at vec4 index 128p; odd row at 128p+64.
        const f32x4 e = __builtin_nontemporal_load(&in[128 * p + l]);
        const f32x4 o = __builtin_nontemporal_load(&in[128 * p + 64 + l]);

        // Output image is 128x128; lane l owns output cols 2l, 2l+1.
        const size_t off = img * (size_t)(128 * 128) + hp * 128 + 2 * l;

        f32x2 ll; ll.x = e.x; ll.y = e.z;
        f32x2 lh; lh.x = e.y; lh.y = e.w;
        f32x2 hl; hl.x = o.x; hl.y = o.z;
        f32x2 hh; hh.x = o.y; hh.y = o.w;

        __builtin_nontemporal_store(ll, reinterpret_cast<f32x2*>(out + off));
        __builtin_nontemporal_store(lh, reinterpret_cast<f32x2*>(out + outsz + off));
        __builtin_nontemporal_store(hl, reinterpret_cast<f32x2*>(out + 2 * outsz + off));
        __builtin_nontemporal_store(hh, reinterpret_cast<f32x2*>(out + 3 * outsz + off));
    }
}

extern "C" void kernel_launch(void* const* d_in, const int* in_sizes, int n_in,
                              void* d_out, int out_size, void* d_ws, size_t ws_size,
                              hipStream_t stream) {
    const float* x = (const float*)d_in[0];
    float* out = (float*)d_out;

    const size_t total  = (size_t)in_sizes[0];      // B*C*H*W = 8*256*256*256
    const size_t nitems = total >> 3;               // 8 floats per work item
    const size_t outsz  = total >> 2;               // each output = total/4

    const int threads = 256;
    const int blocks  = 2048;                        // 8 waves/SIMD across 256 CUs

    deinterleave2x2_kernel<<<blocks, threads, 0, stream>>>(
        reinterpret_cast<const f32x4*>(x), out, nitems, outsz);
}

// Round 4
// 191.593 us; speedup vs baseline: 1.1060x; 1.0168x over previous
//
#include <hip/hip_runtime.h>

// Deinterleave x[B,C,H,W] (fp32, H=W=256) into 4 quadrant tensors:
//   ll = x[:,:,0::2,0::2], lh = x[:,:,0::2,1::2],
//   hl = x[:,:,1::2,0::2], hh = x[:,:,1::2,1::2]
// d_out = [ll | lh | hl | hh] flat, each of size B*C*128*128 floats.
//
// One wave-iteration = one GROUP of 2 row-pairs (4 input rows = 4 KB).
// Lane l loads 4 wave-contiguous 1KB segments (rows 4g..4g+3):
//   e0 = in[256g       + l]   row 4g   (even)
//   o0 = in[256g + 64  + l]   row 4g+1 (odd)
//   e1 = in[256g + 128 + l]   row 4g+2 (even)
//   o1 = in[256g + 192 + l]   row 4g+3 (odd)
// and emits 8x 8B stores, each a 512B-contiguous wave segment into one
// quadrant. 4 loads in flight per iteration (2x MLP of previous version),
// half the loop/index overhead per byte.

typedef float f32x4 __attribute__((ext_vector_type(4)));
typedef float f32x2 __attribute__((ext_vector_type(2)));

__global__ __launch_bounds__(256) void deinterleave2x2_kernel(
    const f32x4* __restrict__ in,    // input viewed as 16B vectors
    float* __restrict__ out,         // base of concatenated outputs
    size_t nitems,                   // total work items = ngroups * 64
    size_t outsz)                    // elements per output tensor
{
    const size_t stride = (size_t)gridDim.x * blockDim.x;
    for (size_t t = (size_t)blockIdx.x * blockDim.x + threadIdx.x;
         t < nitems; t += stride) {
        const size_t l   = t & 63;          // lane-within-group
        const size_t g   = t >> 6;          // group = 2 row-pairs = 4 rows
        const size_t rp  = (g & 63) * 2;    // first row-pair within image
        const size_t img = g >> 6;          // which (b,c) image

        const size_t ib = 256 * g + l;      // input f4 base for this lane
        const f32x4 e0 = in[ib];            // row 4g
        const f32x4 o0 = in[ib + 64];       // row 4g+1
        const f32x4 e1 = in[ib + 128];      // row 4g+2
        const f32x4 o1 = in[ib + 192];      // row 4g+3

        // Output image is 128x128; lane l owns output cols 2l, 2l+1.
        const size_t off0 = img * (size_t)(128 * 128) + rp * 128 + 2 * l;
        const size_t off1 = off0 + 128;

        f32x2 v;
        // row-pair 0
        v.x = e0.x; v.y = e0.z;
        __builtin_nontemporal_store(v, reinterpret_cast<f32x2*>(out + off0));
        v.x = e0.y; v.y = e0.w;
        __builtin_nontemporal_store(v, reinterpret_cast<f32x2*>(out + outsz + off0));
        v.x = o0.x; v.y = o0.z;
        __builtin_nontemporal_store(v, reinterpret_cast<f32x2*>(out + 2 * outsz + off0));
        v.x = o0.y; v.y = o0.w;
        __builtin_nontemporal_store(v, reinterpret_cast<f32x2*>(out + 3 * outsz + off0));
        // row-pair 1
        v.x = e1.x; v.y = e1.z;
        __builtin_nontemporal_store(v, reinterpret_cast<f32x2*>(out + off1));
        v.x = e1.y; v.y = e1.w;
        __builtin_nontemporal_store(v, reinterpret_cast<f32x2*>(out + outsz + off1));
        v.x = o1.x; v.y = o1.z;
        __builtin_nontemporal_store(v, reinterpret_cast<f32x2*>(out + 2 * outsz + off1));
        v.x = o1.y; v.y = o1.w;
        __builtin_nontemporal_store(v, reinterpret_cast<f32x2*>(out + 3 * outsz + off1));
    }
}

extern "C" void kernel_launch(void* const* d_in, const int* in_sizes, int n_in,
                              void* d_out, int out_size, void* d_ws, size_t ws_size,
                              hipStream_t stream) {
    const float* x = (const float*)d_in[0];
    float* out = (float*)d_out;

    const size_t total  = (size_t)in_sizes[0];      // B*C*H*W = 8*256*256*256
    const size_t nitems = total >> 4;               // 16 floats per work item
    const size_t outsz  = total >> 2;               // each output = total/4

    const int threads = 256;
    const int blocks  = 2048;                        // 8 waves/SIMD across 256 CUs

    deinterleave2x2_kernel<<<blocks, threads, 0, stream>>>(
        reinterpret_cast<const f32x4*>(x), out, nitems, outsz);
}